// Round 1
// baseline (162.518 us; speedup 1.0000x reference)
//
#include <hip/hip_runtime.h>
#include <hip/hip_bf16.h>

// LinearPositionInterpolation: out[b, p-1, :] = lerp(value[b, seg, :], value[b, seg+1, :], w)
// where seg = searchsorted(index - index[0], p, 'left') - 1, p in [1, m],
// m = index[n-1] - index[0].
//
// Shapes (from reference setup): n=129 keypoints, dim=256, batch=32, m=4096.
// Output = 32*4096*256 fp32 = 128 MiB -> write-BW bound (~22 us floor at 6.3 TB/s).
//
// Layout: 1 float4 per thread; 64 float4 per output row => one wave == one row,
// so the segment search is wave-uniform and loads/stores are fully coalesced.

#define DIM 256
#define VEC_PER_ROW (DIM / 4)   // 64 float4 per row == 1 wave
#define MAX_N 256               // LDS capacity for the index array

__global__ __launch_bounds__(256) void lpi_kernel(
    const int* __restrict__ index,
    const float* __restrict__ value,
    float* __restrict__ out,
    int n, int m, int batch)
{
    __shared__ int s_idx[MAX_N];

    // Stage index into LDS, rebased so s_idx[0] == 0.
    int base = index[0];
    for (int i = threadIdx.x; i < n; i += blockDim.x) {
        s_idx[i] = index[i] - base;
    }
    __syncthreads();

    int t = blockIdx.x * blockDim.x + threadIdx.x;   // total = batch*m*64 = 8,388,608 < 2^31
    int total = batch * m * VEC_PER_ROW;
    if (t >= total) return;

    int dv  = t & (VEC_PER_ROW - 1);   // float4 index within row
    int row = t >> 6;                  // log2(VEC_PER_ROW) = 6
    int r   = row % m;                 // output row, 0-based
    int b   = row / m;
    int p   = r + 1;                   // query position

    // Binary search: largest seg with s_idx[seg] < p  (wave-uniform; LDS broadcast)
    int lo = 0, hi = n - 1;
    while (lo < hi) {
        int mid = (lo + hi + 1) >> 1;
        if (s_idx[mid] < p) lo = mid; else hi = mid - 1;
    }
    int seg = lo;                      // seg in [0, n-2] since p <= m = s_idx[n-1]

    int x0 = s_idx[seg];
    int x1 = s_idx[seg + 1];
    float w = (float)(p - x0) / (float)(x1 - x0);

    const float4* y0 = (const float4*)(value + (size_t)(b * n + seg) * DIM);
    const float4* y1 = y0 + VEC_PER_ROW;  // row seg+1 is contiguous

    float4 a = y0[dv];
    float4 c = y1[dv];

    float4 o;
    o.x = a.x + (c.x - a.x) * w;
    o.y = a.y + (c.y - a.y) * w;
    o.z = a.z + (c.z - a.z) * w;
    o.w = a.w + (c.w - a.w) * w;

    float4* op = (float4*)(out + (size_t)(b * m + r) * DIM);
    op[dv] = o;
}

extern "C" void kernel_launch(void* const* d_in, const int* in_sizes, int n_in,
                              void* d_out, int out_size, void* d_ws, size_t ws_size,
                              hipStream_t stream) {
    const int*   index = (const int*)d_in[0];
    const float* value = (const float*)d_in[1];
    float*       out   = (float*)d_out;

    int n  = in_sizes[0];                 // 129
    int bd = in_sizes[1] / n;             // batch * dim = 8192
    const int dim = DIM;                  // 256 (per reference setup)
    int batch = bd / dim;                 // 32
    int m = out_size / bd;                // 4096

    int total = batch * m * VEC_PER_ROW;  // one float4 per thread
    int block = 256;
    int grid  = (total + block - 1) / block;

    lpi_kernel<<<grid, block, 0, stream>>>(index, value, out, n, m, batch);
}

// Round 3
// 144.191 us; speedup vs baseline: 1.1271x; 1.1271x over previous
//
#include <hip/hip_runtime.h>
#include <hip/hip_bf16.h>

// LinearPositionInterpolation: out[b, p-1, :] = lerp(value[b, seg, :], value[b, seg+1, :], w)
// seg = searchsorted(index - index[0], p, 'left') - 1, p in [1, m], m = index[n-1]-index[0].
//
// R1 restructure: one block per (batch, segment). No per-thread search — seg is
// blockIdx. Each lane loads its float4 of y0/y1 ONCE, then streams the segment's
// output rows (w varies, data reused). Kernel is pure coalesced streaming stores:
// 134 MB out + 4.2 MB in -> ~22 us floor at 6.3 TB/s.
//
// R2 fix: __builtin_nontemporal_store needs a Clang native vector type, not
// HIP's struct float4 -> use ext_vector_type(4).

#define DIM 256
#define VEC_PER_ROW (DIM / 4)   // 64 float4 per row == 1 wave per row

typedef float vfloat4 __attribute__((ext_vector_type(4)));

__global__ __launch_bounds__(256) void lpi_kernel(
    const int* __restrict__ index,
    const float* __restrict__ value,
    float* __restrict__ out,
    int n, int m)
{
    int nseg = n - 1;
    int seg  = blockIdx.x % nseg;        // segment id (wave-uniform, scalar)
    int b    = blockIdx.x / nseg;        // batch id

    int base = index[0];
    int x0   = index[seg]     - base;    // tiny, L2-cached
    int x1   = index[seg + 1] - base;
    int len  = x1 - x0;                  // positions in this segment

    int lane = threadIdx.x & 63;         // float4 index within the 256-wide row
    int wv   = threadIdx.x >> 6;         // wave id within block (0..3)

    const vfloat4* y0 = (const vfloat4*)(value + (size_t)(b * n + seg) * DIM);
    const vfloat4* y1 = y0 + VEC_PER_ROW; // row seg+1 contiguous after row seg

    vfloat4 a = y0[lane];
    vfloat4 c = y1[lane];
    vfloat4 d = c - a;                   // diff = y1 - y0, computed once

    float flen = (float)len;

    // rows r = x0 + k  (i.e. p = x0 + k + 1), k in [0, len)
    for (int k = wv; k < len; k += 4) {
        float w = (float)(k + 1) / flen; // == (p - x0)/(x1 - x0), same math as ref
        vfloat4 o = a + d * w;
        vfloat4* op = (vfloat4*)(out + (size_t)(b * m + x0 + k) * DIM);
        __builtin_nontemporal_store(o, op + lane);
    }
}

extern "C" void kernel_launch(void* const* d_in, const int* in_sizes, int n_in,
                              void* d_out, int out_size, void* d_ws, size_t ws_size,
                              hipStream_t stream) {
    const int*   index = (const int*)d_in[0];
    const float* value = (const float*)d_in[1];
    float*       out   = (float*)d_out;

    int n  = in_sizes[0];                 // 129
    int bd = in_sizes[1] / n;             // batch * dim = 8192
    const int dim = DIM;                  // 256 (per reference setup)
    int batch = bd / dim;                 // 32
    int m = out_size / bd;                // 4096

    int grid = batch * (n - 1);           // 4096 blocks: one per (batch, segment)
    lpi_kernel<<<grid, 256, 0, stream>>>(index, value, out, n, m);
}